// Round 8
// baseline (188.896 us; speedup 1.0000x reference)
//
#include <hip/hip_runtime.h>
#include <hip/hip_bf16.h>

#define BLOCK   512     // 8 waves; wave w owns channels w*16..w*16+15, all 4 gates
#define NSAMP   16      // samples per tile
#define NTILE   2       // independent sample-tiles per block (ILP streams)
#define HDIM    128
#define DDIM    16
#define NOBJ    6
#define NSLOT   14

typedef __attribute__((ext_vector_type(8))) short bf16x8;
typedef __attribute__((ext_vector_type(4))) float f32x4;

constexpr int pc6(int m)  { int c = 0; for (int i = 0; i < 6; ++i) c += (m >> i) & 1; return c; }
constexpr int msb6(int m) { int b = -1; for (int i = 0; i < 6; ++i) if (m & (1 << i)) b = i; return b; }

// ---- Grouped plan (verified R4): children grouped by PARENT so W_hh*h_P (zh)
// is computed ONCE per parent. Parent slot freeable once zh/c read (cached in
// regs); allocator inserts recycle barriers when the 14-slot pool is full.
struct GChild { int jo, sl; bool bar; };
struct Plan3 {
    int    gps [32];    // parent slot per group (-1 for the root pseudo-parent)
    int    gbeg[33];    // child range per group: [gbeg[g], gbeg[g+1])
    GChild ch  [63];
    int    lvlG[8];     // group range per level d: [lvlG[d], lvlG[d+1])
    bool   ok;
};
constexpr Plan3 make_plan3() {
    Plan3 P{};
    P.ok = true;
    int  slotOf[64] = {};
    bool busy[NSLOT] = {};
    int  pendingFree[NSLOT] = {};   // parent slots read, freeable at next barrier
    int  npend = 0;
    int  g = 0, cidx = 0;
    for (int d = 1; d <= 6; ++d) {
        P.lvlG[d] = g;
        for (int Pm = 0; Pm < 64; ++Pm) {
            if (pc6(Pm) != d - 1) continue;
            if (Pm != 0 && msb6(Pm) == 5) continue;      // leaves have no children
            P.gps[g]  = (Pm == 0) ? -1 : slotOf[Pm];
            P.gbeg[g] = cidx;
            if (Pm != 0) pendingFree[npend++] = slotOf[Pm];   // zh/c read at group start
            const int j0 = (Pm == 0) ? 0 : msb6(Pm) + 1;
            for (int j = j0; j <= 5; ++j) {
                const int M = Pm | (1 << j);
                P.ch[cidx].jo  = j;
                P.ch[cidx].bar = false;
                int sl = -1;
                if (j < 5) {
                    int fs = -1;
                    for (int s = 0; s < NSLOT; ++s) if (!busy[s]) { fs = s; break; }
                    if (fs < 0) {   // recycle barrier: free all pending parents
                        P.ch[cidx].bar = true;
                        if (npend == 0) P.ok = false;
                        for (int i = 0; i < npend; ++i) busy[pendingFree[i]] = false;
                        npend = 0;
                        for (int s = 0; s < NSLOT; ++s) if (!busy[s]) { fs = s; break; }
                        if (fs < 0) P.ok = false;
                    }
                    if (fs >= 0) { busy[fs] = true; slotOf[M] = fs; sl = fs; }
                }
                P.ch[cidx].sl = sl;
                ++cidx;
            }
            ++g;
        }
        // level-end barrier frees all parents read during this level
        for (int i = 0; i < npend; ++i) busy[pendingFree[i]] = false;
        npend = 0;
    }
    P.lvlG[7] = g;
    P.gbeg[g] = cidx;
    if (g != 32 || cidx != 63) P.ok = false;
    return P;
}
constexpr Plan3 PL3 = make_plan3();
static_assert(PL3.ok, "plan allocation failed");
static_assert(PL3.lvlG[7] == 32, "32 groups expected");
static_assert(PL3.gbeg[32] == 63, "63 children expected");

#define LOG2E   1.44269504f
#define TWOL2E  2.88539008f
#define SLOT_SH (16 * NTILE * NSAMP * 8)    // shorts per h slot (8 KB at NTILE=2)

__device__ __forceinline__ unsigned short f2bf(float x) {
    union { float f; unsigned int u; } a; a.f = x;
    unsigned int r = (a.u + 0x7FFFu + ((a.u >> 16) & 1u)) >> 16;
    return (unsigned short)r;
}
__device__ __forceinline__ unsigned pk2(float a, float b) {
    union { __hip_bfloat162 h; unsigned u; } z;
    z.h = __float22bfloat162_rn(float2{a, b});
    return z.u;
}
__device__ __forceinline__ float bflo(unsigned p) {
    union { unsigned u; float f; } a; a.u = p << 16; return a.f;
}
__device__ __forceinline__ float bfhi(unsigned p) {
    union { unsigned u; float f; } a; a.u = p & 0xFFFF0000u; return a.f;
}

// R8 design: TWO independent sample-tiles per wave (ILP instead of TLP).
//   R4-R7 invariant (135-141 us over 4 instruction mixes) = latency floor at
//   2 waves/SIMD; 4 waves/SIMD unreachable (total VGPR+AGPR ~176 > 128).
//   At 2 waves/SIMD each wave owns 256 total regs; the slack funds a second
//   stream whose chains hide the first's ds_read/MFMA/exp2 latency.  Weights
//   (80 VGPRs) are SHARED between streams; only c (bf16 uint2, R0-verified),
//   zh/acc (AGPR side), mh duplicate.  Grid halves to 256 = 1 block/CU.
// h pool: hs[((slot*16 + kslot)*32 + tile*16 + n)*8 + j], kslot as before.

__global__ __launch_bounds__(BLOCK)
__attribute__((amdgpu_waves_per_eu(2, 4)))   // attested no-scratch envelope
void subset_lstm_skew_kernel(
    const float* __restrict__ x_input,
    const float* __restrict__ W_ih,
    const float* __restrict__ W_hh,
    const float* __restrict__ b_ih,
    const float* __restrict__ b_hh,
    const float* __restrict__ fc1_W,
    const float* __restrict__ fc1_b,
    const float* __restrict__ fc2_W,
    const float* __restrict__ fc2_b,
    float* __restrict__ out)
{
    __shared__ __align__(16) unsigned short hs[NSLOT * SLOT_SH];              // 112 KB
    __shared__ __align__(16) unsigned short xb[NOBJ * 4 * NTILE * NSAMP * 8]; // 12 KB
    float* s_maxh  = (float*)hs;                 // 16 KB (post-LSTM alias)
    float* s_fc1   = (float*)(hs + 8192);        // 32 KB (post-LSTM alias)
    float* s_logit = (float*)xb;

    const int t      = threadIdx.x;
    const int w      = t >> 6;
    const int lane   = t & 63;
    const int quad   = lane >> 4;
    const int m16    = lane & 15;
    const int s_base = blockIdx.x * (NTILE * NSAMP);

    // ---- x B-chunks: xb[obj][quad'][n5][j], n5 = tile*16+n; q2 j0=1.0, q3 zero ----
    for (int idx = t; idx < NOBJ * 4 * NTILE * NSAMP * 8; idx += BLOCK) {
        const int j = idx & 7, n5 = (idx >> 3) & 31, q = (idx >> 8) & 3, obj = idx >> 10;
        float v;
        if (q < 2) v = x_input[(s_base + n5) * (NOBJ * DDIM) + obj * DDIM + q * 8 + j];
        else       v = (q == 2 && j == 0) ? 1.0f : 0.0f;
        xb[idx] = f2bf(v);
    }

    // ---- persistent A-frags wf[gate][chunk], PRE-SCALED (verified R8-R13) ----
    bf16x8 wf[4][5];
    #pragma unroll
    for (int g = 0; g < 4; ++g) {
        const float sc = (g == 2) ? TWOL2E : -LOG2E;
        const int grow = g * HDIM + w * 16 + m16;
        const float* whr = W_hh + grow * HDIM;
        const float* wir = W_ih + grow * DDIM;
        #pragma unroll
        for (int q = 0; q < 4; ++q) {
            union { unsigned short u[8]; bf16x8 v; } pk;
            #pragma unroll
            for (int j = 0; j < 8; ++j)
                pk.u[j] = f2bf(sc * whr[q * 32 + quad * 8 + j]);
            wf[g][q] = pk.v;
        }
        {
            union { unsigned short u[8]; bf16x8 v; } pk;
            #pragma unroll
            for (int j = 0; j < 8; ++j) {
                float v = 0.0f;
                if (quad < 2) v = sc * wir[quad * 8 + j];
                else if (quad == 2 && j == 0) v = sc * (b_ih[grow] + b_hh[grow]);
                pk.u[j] = f2bf(v);
            }
            wf[g][4] = pk.v;
        }
    }

    float mh[NTILE][4];
    #pragma unroll
    for (int tl = 0; tl < NTILE; ++tl)
        #pragma unroll
        for (int r = 0; r < 4; ++r) mh[tl][r] = -1e30f;
    const int kslot = w * 2 + (quad >> 1);
    uint2 c_pk[NTILE][NSLOT];   // bf16-packed c, lane-private, static idx

    // fused pointwise tail for one tile (verified R9-R13 math)
    auto pw_tail = [&](int tl, const f32x4 (&acc)[4], const float (&cp4)[4], int sl) {
        float cn4[4], hn4[4];
        #pragma unroll
        for (int r = 0; r < 4; ++r) {
            const float u  = 1.0f + __builtin_amdgcn_exp2f(acc[0][r]);
            const float q  = 1.0f + __builtin_amdgcn_exp2f(acc[1][r]);
            const float v  = 1.0f + __builtin_amdgcn_exp2f(acc[2][r]);
            const float qo = 1.0f + __builtin_amdgcn_exp2f(acc[3][r]);
            const float uv  = u * v;
            const float num = fmaf(q, v - 2.0f, cp4[r] * uv);
            const float cn  = num * __builtin_amdgcn_rcpf(q * uv);
            const float wt  = 1.0f + __builtin_amdgcn_exp2f(TWOL2E * cn);
            const float h   = (wt - 2.0f) * __builtin_amdgcn_rcpf(qo * wt);
            cn4[r] = cn; hn4[r] = h;
            mh[tl][r] = fmaxf(mh[tl][r], h);
        }
        if (sl >= 0) {
            c_pk[tl][sl].x = pk2(cn4[0], cn4[1]);
            c_pk[tl][sl].y = pk2(cn4[2], cn4[3]);
            uint2 hw; hw.x = pk2(hn4[0], hn4[1]); hw.y = pk2(hn4[2], hn4[3]);
            *(uint2*)&hs[((sl * 16 + kslot) * (NTILE * NSAMP) + tl * NSAMP + m16) * 8
                         + (quad & 1) * 4] = hw;
        }
    };

    // ---- main loop: per level, per parent-group; both tiles in flight ----
    #pragma unroll
    for (int d = 1; d <= 6; ++d) {
        __syncthreads();
        const int gBeg = PL3.lvlG[d];
        const int gEnd = PL3.lvlG[d + 1];
        #pragma unroll
        for (int gi = gBeg; gi < gEnd; ++gi) {
            const int ps = PL3.gps[gi];
            // -- zh chains (16 MFMA x 2 tiles, independent) + parent c --
            f32x4 zh[NTILE][4];
            float cp4[NTILE][4];
            #pragma unroll
            for (int tl = 0; tl < NTILE; ++tl)
                #pragma unroll
                for (int g2 = 0; g2 < 4; ++g2) zh[tl][g2] = f32x4{0.f, 0.f, 0.f, 0.f};
            if (ps >= 0) {
                #pragma unroll
                for (int q = 0; q < 4; ++q) {
                    #pragma unroll
                    for (int tl = 0; tl < NTILE; ++tl) {
                        const bf16x8 bh = *(const bf16x8*)
                            &hs[((ps * 16 + q * 4 + quad) * (NTILE * NSAMP)
                                 + tl * NSAMP + m16) * 8];
                        #pragma unroll
                        for (int g2 = 0; g2 < 4; ++g2)
                            zh[tl][g2] = __builtin_amdgcn_mfma_f32_16x16x32_bf16(
                                wf[g2][q], bh, zh[tl][g2], 0, 0, 0);
                    }
                }
                #pragma unroll
                for (int tl = 0; tl < NTILE; ++tl) {
                    cp4[tl][0] = bflo(c_pk[tl][ps].x);
                    cp4[tl][1] = bfhi(c_pk[tl][ps].x);
                    cp4[tl][2] = bflo(c_pk[tl][ps].y);
                    cp4[tl][3] = bfhi(c_pk[tl][ps].y);
                }
            } else {
                #pragma unroll
                for (int tl = 0; tl < NTILE; ++tl)
                    #pragma unroll
                    for (int r = 0; r < 4; ++r) cp4[tl][r] = 0.0f;
            }
            // -- children: per tile x-MFMA (C=zh) then pointwise; streams interleave --
            #pragma unroll
            for (int ci = PL3.gbeg[gi]; ci < PL3.gbeg[gi + 1]; ++ci) {
                if (PL3.ch[ci].bar) __syncthreads();   // recycle barrier (constexpr)
                const int jo = PL3.ch[ci].jo;
                const int sl = PL3.ch[ci].sl;
                f32x4 acc[NTILE][4];
                #pragma unroll
                for (int tl = 0; tl < NTILE; ++tl) {
                    const bf16x8 bfx = *(const bf16x8*)
                        &xb[((jo * 4 + quad) * (NTILE * NSAMP) + tl * NSAMP + m16) * 8];
                    #pragma unroll
                    for (int g2 = 0; g2 < 4; ++g2)
                        acc[tl][g2] = __builtin_amdgcn_mfma_f32_16x16x32_bf16(
                            wf[g2][4], bfx, zh[tl][g2], 0, 0, 0);
                }
                #pragma unroll
                for (int tl = 0; tl < NTILE; ++tl)
                    pw_tail(tl, acc[tl], cp4[tl], sl);
            }
        }
    }

    __syncthreads();   // pools dead; reuse hs for epilogue
    #pragma unroll
    for (int tl = 0; tl < NTILE; ++tl) {
        float4 v; v.x = mh[tl][0]; v.y = mh[tl][1]; v.z = mh[tl][2]; v.w = mh[tl][3];
        *(float4*)&s_maxh[(tl * NSAMP + m16) * HDIM + w * 16 + quad * 4] = v;
    }
    __syncthreads();

    // ---- FC1: f = t&255, sample half sh = t>>8 (16 samples each) ----
    {
        const int f  = t & 255;
        const int sh = t >> 8;
        float a1[16];
        #pragma unroll
        for (int s = 0; s < 16; ++s) a1[s] = fc1_b[f];
        for (int k4 = 0; k4 < HDIM / 4; ++k4) {
            const float4 wv = *(const float4*)&fc1_W[f * HDIM + k4 * 4];
            #pragma unroll
            for (int s = 0; s < 16; ++s) {
                const float4 h4 = *(const float4*)&s_maxh[(sh * 16 + s) * HDIM + k4 * 4];
                a1[s] += wv.x * h4.x + wv.y * h4.y + wv.z * h4.z + wv.w * h4.w;
            }
        }
        #pragma unroll
        for (int s = 0; s < 16; ++s)
            s_fc1[(sh * 16 + s) * 256 + f] = fmaxf(a1[s], 0.0f);
    }
    __syncthreads();

    if (t < NTILE * NSAMP * 10) {
        const int s = t / 10, a = t % 10;
        float acc2 = fc2_b[a];
        for (int f4 = 0; f4 < 256 / 4; ++f4) {
            const float4 wv = *(const float4*)&fc2_W[a * 256 + f4 * 4];
            const float4 v  = *(const float4*)&s_fc1[s * 256 + f4 * 4];
            acc2 += wv.x * v.x + wv.y * v.y + wv.z * v.z + wv.w * v.w;
        }
        s_logit[s * 10 + a] = acc2;
    }
    __syncthreads();

    if (t < NTILE * NSAMP) {
        float m = -1e30f;
        #pragma unroll
        for (int a = 0; a < 10; ++a) m = fmaxf(m, s_logit[t * 10 + a]);
        float sum = 0.0f;
        #pragma unroll
        for (int a = 0; a < 10; ++a) sum += __expf(s_logit[t * 10 + a] - m);
        const float lse = m + __logf(sum);
        #pragma unroll
        for (int a = 0; a < 10; ++a)
            out[(s_base + t) * 10 + a] = s_logit[t * 10 + a] - lse;
    }
}

extern "C" void kernel_launch(void* const* d_in, const int* in_sizes, int n_in,
                              void* d_out, int out_size, void* d_ws, size_t ws_size,
                              hipStream_t stream)
{
    (void)d_ws; (void)ws_size; (void)n_in; (void)out_size;

    const float* x   = (const float*)d_in[0];
    const float* Wih = (const float*)d_in[1];
    const float* Whh = (const float*)d_in[2];
    const float* bih = (const float*)d_in[3];
    const float* bhh = (const float*)d_in[4];
    const float* f1w = (const float*)d_in[5];
    const float* f1b = (const float*)d_in[6];
    const float* f2w = (const float*)d_in[7];
    const float* f2b = (const float*)d_in[8];

    const int mb = in_sizes[0] / (NOBJ * DDIM);   // 8192
    dim3 grid(mb / (NTILE * NSAMP)), block(BLOCK);   // 256 blocks = 1 per CU
    subset_lstm_skew_kernel<<<grid, block, 0, stream>>>(
        x, Wih, Whh, bih, bhh, f1w, f1b, f2w, f2b, (float*)d_out);
}